// Round 2
// baseline (1909.053 us; speedup 1.0000x reference)
//
#include <hip/hip_runtime.h>
#include <math.h>

#define U_DIM 8001
#define I_DIM 16001
#define B_DIM 8192
#define UT    32                        // rows per u-tile
#define NBT   4                         // b-tiles
#define TB    (B_DIM / NBT)             // 2048 samples per block
#define NUT   ((U_DIM + UT - 1) / UT)   // 251 u-tiles

// ---------------------------------------------------------------------------
// Fused kernel: block = (u-tile, b-tile). For each row u in the tile:
//   1. stage the full row (64 KB) into LDS with coalesced loads, summing
//      nonzeros on the way (row bias computed inline — no separate pass)
//   2. every thread gathers its items from LDS and accumulates
//      sv * (row[it] - ub)
// Partials land in a zeroed accumulator via atomicAdd (251 adds/address).
// ---------------------------------------------------------------------------
__global__ __launch_bounds__(1024)
void fused_kernel(const int* __restrict__ user, const int* __restrict__ item,
                  const float* __restrict__ R, const float* __restrict__ S,
                  float* __restrict__ accum) {
    __shared__ float rowbuf[I_DIM];   // 64004 B
    __shared__ float red_s[16];
    __shared__ int   red_c[16];

    const int ut = blockIdx.x >> 2;   // 4 b-tiles of the same u-tile are
    const int bt = blockIdx.x & 3;    // adjacent -> co-scheduled -> L3 dedup
    const int u0 = ut * UT;
    const int nrows = min(UT, U_DIM - u0);
    const int tid  = threadIdx.x;
    const int wid  = tid >> 6;
    const int lane = tid & 63;

    const int b0 = bt * TB + tid;     // thread owns 2 samples
    const int b1 = b0 + 1024;
    const int it0 = item[b0], usr0 = user[b0];
    const int it1 = item[b1], usr1 = user[b1];
    const float* s0p = S + (size_t)usr0 * U_DIM;
    const float* s1p = S + (size_t)usr1 * U_DIM;

    float acc0 = 0.f, acc1 = 0.f;

    for (int r = 0; r < nrows; ++r) {
        const int u = u0 + r;
        const float* rp = R + (size_t)u * I_DIM;

        // stage row + local nonzero sum/count
        float s = 0.f; int c = 0;
        for (int i = tid; i < I_DIM; i += 1024) {
            float v = rp[i];
            rowbuf[i] = v;
            s += v;
            c += (v != 0.f);
        }
        // wave64 reduce
        #pragma unroll
        for (int off = 32; off > 0; off >>= 1) {
            s += __shfl_down(s, off, 64);
            c += __shfl_down(c, off, 64);
        }
        if (lane == 0) { red_s[wid] = s; red_c[wid] = c; }
        __syncthreads();                       // rowbuf + red complete

        // every thread folds the 16 wave partials (broadcast LDS reads)
        float Sr = 0.f; int Cr = 0;
        #pragma unroll
        for (int k = 0; k < 16; ++k) { Sr += red_s[k]; Cr += red_c[k]; }
        const float ub = (Cr > 0) ? Sr / (float)Cr : 0.f;

        // S walks contiguously in u per thread -> line reused 16x (L1/L2)
        const float sv0 = s0p[u];
        const float sv1 = s1p[u];
        acc0 += sv0 * (rowbuf[it0] - ub);
        acc1 += sv1 * (rowbuf[it1] - ub);
        __syncthreads();                       // before restaging rowbuf/red
    }

    atomicAdd(&accum[b0], acc0);
    atomicAdd(&accum[b1], acc1);
}

// ---------------------------------------------------------------------------
__global__ void finish_kernel(const float* __restrict__ accum,
                              const int* __restrict__ user,
                              const int* __restrict__ item,
                              const float* __restrict__ ubias,
                              const float* __restrict__ ibias,
                              const float* __restrict__ gb,
                              float* __restrict__ out) {
    const int b = blockIdx.x * blockDim.x + threadIdx.x;
    if (b < B_DIM) {
        float pred = accum[b] + ubias[user[b]] + ibias[item[b]] + gb[0];
        out[b] = 5.f / (1.f + expf(-pred));
    }
}

// ---------------------------------------------------------------------------
extern "C" void kernel_launch(void* const* d_in, const int* in_sizes, int n_in,
                              void* d_out, int out_size, void* d_ws, size_t ws_size,
                              hipStream_t stream) {
    const int*   user = (const int*)  d_in[0];
    const int*   item = (const int*)  d_in[1];
    const float* R    = (const float*)d_in[2];
    const float* S    = (const float*)d_in[3];
    const float* ubia = (const float*)d_in[4];
    const float* ibia = (const float*)d_in[5];
    const float* gb   = (const float*)d_in[6];
    float* out   = (float*)d_out;
    float* accum = (float*)d_ws;      // B_DIM floats

    hipMemsetAsync(accum, 0, B_DIM * sizeof(float), stream);
    fused_kernel<<<NUT * NBT, 1024, 0, stream>>>(user, item, R, S, accum);
    finish_kernel<<<(B_DIM + 255) / 256, 256, 0, stream>>>(accum, user, item,
                                                           ubia, ibia, gb, out);
}

// Round 3
// 965.443 us; speedup vs baseline: 1.9774x; 1.9774x over previous
//
#include <hip/hip_runtime.h>
#include <math.h>

#define U_DIM 8001
#define I_DIM 16001
#define B_DIM 8192

// ---------------------------------------------------------------------------
// Phase 1: one block per row u. Stage row into LDS (coalesced, once total),
// compute nonzero-mean ub inline, then write the gathered adjusted row
// Ag[u_local, b] = row[item[b]] - ub, coalesced across b.
// ---------------------------------------------------------------------------
__global__ __launch_bounds__(1024)
void gather_kernel(const float* __restrict__ R, const int* __restrict__ item,
                   float* __restrict__ Ag, int row0) {
    __shared__ float rowbuf[I_DIM];   // 64004 B
    __shared__ float red_s[16];
    __shared__ int   red_c[16];

    const int u   = row0 + blockIdx.x;
    const int tid = threadIdx.x;
    const float* rp = R + (size_t)u * I_DIM;

    float s = 0.f; int c = 0;
    // element alignment phase of the row: (u*16001) mod 4 == u mod 4
    const int pre  = (4 - (u & 3)) & 3;
    const int nvec = (I_DIM - pre) >> 2;
    const int vend = pre + (nvec << 2);

    for (int i = tid; i < pre; i += 1024) {
        float v = rp[i]; rowbuf[i] = v; s += v; c += (v != 0.f);
    }
    const float4* rv = (const float4*)(rp + pre);
    for (int i = tid; i < nvec; i += 1024) {
        float4 v = rv[i];
        const int base = pre + (i << 2);
        rowbuf[base    ] = v.x;      // scalar LDS writes: rowbuf+base may be
        rowbuf[base + 1] = v.y;      // 16B-misaligned when pre != 0
        rowbuf[base + 2] = v.z;
        rowbuf[base + 3] = v.w;
        s += v.x + v.y + v.z + v.w;
        c += (v.x != 0.f) + (v.y != 0.f) + (v.z != 0.f) + (v.w != 0.f);
    }
    for (int i = vend + tid; i < I_DIM; i += 1024) {
        float v = rp[i]; rowbuf[i] = v; s += v; c += (v != 0.f);
    }

    #pragma unroll
    for (int off = 32; off > 0; off >>= 1) {
        s += __shfl_down(s, off, 64);
        c += __shfl_down(c, off, 64);
    }
    const int wid  = tid >> 6;
    const int lane = tid & 63;
    if (lane == 0) { red_s[wid] = s; red_c[wid] = c; }
    __syncthreads();

    float Sr = 0.f; int Cr = 0;
    #pragma unroll
    for (int k = 0; k < 16; ++k) { Sr += red_s[k]; Cr += red_c[k]; }
    const float ub = (Cr > 0) ? Sr / (float)Cr : 0.f;

    float* arow = Ag + (size_t)blockIdx.x * B_DIM;
    for (int b = tid; b < B_DIM; b += 1024)
        arow[b] = rowbuf[item[b]] - ub;     // LDS gather, coalesced store
}

// ---------------------------------------------------------------------------
// Phase 2: grid (32 b-blocks, nuc u-chunks), 256 threads. Thread owns one b.
// Ag reads coalesced across lanes; S reads walk contiguously per thread with
// a 16 KB/block active line set (L1-resident, 16x reuse per line).
// ---------------------------------------------------------------------------
__global__ __launch_bounds__(256)
void dot2_kernel(const float* __restrict__ S, const int* __restrict__ user,
                 const float* __restrict__ Ag, float* __restrict__ accum,
                 int row0, int nrows, int uchunk) {
    const int b   = blockIdx.x * 256 + threadIdx.x;
    const int usr = user[b];
    const float* srow = S + (size_t)usr * U_DIM + row0;

    const int ulo = blockIdx.y * uchunk;
    const int uhi = min(nrows, ulo + uchunk);

    float acc = 0.f;
    #pragma unroll 4
    for (int r = ulo; r < uhi; ++r)
        acc += srow[r] * Ag[(size_t)r * B_DIM + b];

    atomicAdd(&accum[b], acc);
}

// ---------------------------------------------------------------------------
__global__ void finish_kernel(const float* __restrict__ accum,
                              const int* __restrict__ user,
                              const int* __restrict__ item,
                              const float* __restrict__ ubias,
                              const float* __restrict__ ibias,
                              const float* __restrict__ gb,
                              float* __restrict__ out) {
    const int b = blockIdx.x * blockDim.x + threadIdx.x;
    if (b < B_DIM) {
        float pred = accum[b] + ubias[user[b]] + ibias[item[b]] + gb[0];
        out[b] = 5.f / (1.f + expf(-pred));
    }
}

// ---------------------------------------------------------------------------
extern "C" void kernel_launch(void* const* d_in, const int* in_sizes, int n_in,
                              void* d_out, int out_size, void* d_ws, size_t ws_size,
                              hipStream_t stream) {
    const int*   user = (const int*)  d_in[0];
    const int*   item = (const int*)  d_in[1];
    const float* R    = (const float*)d_in[2];
    const float* S    = (const float*)d_in[3];
    const float* ubia = (const float*)d_in[4];
    const float* ibia = (const float*)d_in[5];
    const float* gb   = (const float*)d_in[6];
    float* out   = (float*)d_out;

    float* accum = (float*)d_ws;                 // B_DIM floats
    float* Ag    = (float*)d_ws + B_DIM;         // row-chunked gather buffer

    // rows per chunk limited by workspace (stream-ordered chunking if small)
    size_t rg_bytes = (ws_size > (size_t)B_DIM * 4) ? ws_size - (size_t)B_DIM * 4 : 0;
    int max_rows = (int)(rg_bytes / ((size_t)B_DIM * 4));
    if (max_rows > U_DIM) max_rows = U_DIM;
    if (max_rows < 1)     max_rows = 1;

    hipMemsetAsync(accum, 0, B_DIM * sizeof(float), stream);

    for (int row0 = 0; row0 < U_DIM; row0 += max_rows) {
        const int nrows = min(max_rows, U_DIM - row0);
        gather_kernel<<<nrows, 1024, 0, stream>>>(R, item, Ag, row0);
        const int uchunk = 250;
        const int nuc = (nrows + uchunk - 1) / uchunk;
        dot2_kernel<<<dim3(B_DIM / 256, nuc), 256, 0, stream>>>(S, user, Ag, accum,
                                                                row0, nrows, uchunk);
    }

    finish_kernel<<<(B_DIM + 255) / 256, 256, 0, stream>>>(accum, user, item,
                                                           ubia, ibia, gb, out);
}

// Round 4
// 933.536 us; speedup vs baseline: 2.0450x; 1.0342x over previous
//
#include <hip/hip_runtime.h>
#include <math.h>

#define U_DIM 8001
#define I_DIM 16001
#define B_DIM 8192

__device__ __forceinline__ unsigned short f32_to_bf16_rne(float f) {
    union { float f; unsigned int u; } v; v.f = f;
    unsigned int r = v.u + 0x7fffu + ((v.u >> 16) & 1u);   // round-nearest-even
    return (unsigned short)(r >> 16);
}
__device__ __forceinline__ float bf16_to_f32(unsigned short h) {
    union { unsigned int u; float f; } v; v.u = ((unsigned int)h) << 16;
    return v.f;
}

// ---------------------------------------------------------------------------
// Phase 1: one block per row u. Stage row into LDS (coalesced, R read once),
// compute nonzero-mean ub inline, write gathered adjusted row as bf16 with
// nontemporal stores (streaming data — keep it out of L2/L3 so S stays hot).
// ---------------------------------------------------------------------------
__global__ __launch_bounds__(1024)
void gather_kernel(const float* __restrict__ R, const int* __restrict__ item,
                   unsigned short* __restrict__ Ag, int row0) {
    __shared__ float rowbuf[I_DIM];   // 64004 B
    __shared__ float red_s[16];
    __shared__ int   red_c[16];

    const int u   = row0 + blockIdx.x;
    const int tid = threadIdx.x;
    const float* rp = R + (size_t)u * I_DIM;

    float s = 0.f; int c = 0;
    const int pre  = (4 - (u & 3)) & 3;           // row align phase = u mod 4
    const int nvec = (I_DIM - pre) >> 2;
    const int vend = pre + (nvec << 2);

    for (int i = tid; i < pre; i += 1024) {
        float v = rp[i]; rowbuf[i] = v; s += v; c += (v != 0.f);
    }
    const float4* rv = (const float4*)(rp + pre);
    for (int i = tid; i < nvec; i += 1024) {
        float4 v = rv[i];
        const int base = pre + (i << 2);
        rowbuf[base    ] = v.x;
        rowbuf[base + 1] = v.y;
        rowbuf[base + 2] = v.z;
        rowbuf[base + 3] = v.w;
        s += v.x + v.y + v.z + v.w;
        c += (v.x != 0.f) + (v.y != 0.f) + (v.z != 0.f) + (v.w != 0.f);
    }
    for (int i = vend + tid; i < I_DIM; i += 1024) {
        float v = rp[i]; rowbuf[i] = v; s += v; c += (v != 0.f);
    }

    #pragma unroll
    for (int off = 32; off > 0; off >>= 1) {
        s += __shfl_down(s, off, 64);
        c += __shfl_down(c, off, 64);
    }
    const int wid  = tid >> 6;
    const int lane = tid & 63;
    if (lane == 0) { red_s[wid] = s; red_c[wid] = c; }
    __syncthreads();

    float Sr = 0.f; int Cr = 0;
    #pragma unroll
    for (int k = 0; k < 16; ++k) { Sr += red_s[k]; Cr += red_c[k]; }
    const float ub = (Cr > 0) ? Sr / (float)Cr : 0.f;

    unsigned short* arow = Ag + (size_t)blockIdx.x * B_DIM;
    for (int b = tid; b < B_DIM; b += 1024) {
        float ad = rowbuf[item[b]] - ub;          // LDS gather
        __builtin_nontemporal_store(f32_to_bf16_rne(ad), &arow[b]);
    }
}

// ---------------------------------------------------------------------------
// Phase 2: grid (32 b-blocks, nuc u-chunks), 256 threads; thread owns one b.
// Ag: bf16, lane-coalesced, nontemporal (read-once). S: per-thread contiguous
// walk, 16 KB active line set per block -> L1-resident, 16x reuse per line.
// ---------------------------------------------------------------------------
__global__ __launch_bounds__(256)
void dot2_kernel(const float* __restrict__ S, const int* __restrict__ user,
                 const unsigned short* __restrict__ Ag, float* __restrict__ accum,
                 int row0, int nrows, int uchunk) {
    const int b   = blockIdx.x * 256 + threadIdx.x;
    const int usr = user[b];
    const float* srow = S + (size_t)usr * U_DIM + row0;

    const int ulo = blockIdx.y * uchunk;
    const int uhi = min(nrows, ulo + uchunk);

    float acc = 0.f;
    #pragma unroll 4
    for (int r = ulo; r < uhi; ++r) {
        unsigned short h = __builtin_nontemporal_load(&Ag[(size_t)r * B_DIM + b]);
        acc += srow[r] * bf16_to_f32(h);
    }
    atomicAdd(&accum[b], acc);
}

// ---------------------------------------------------------------------------
__global__ void finish_kernel(const float* __restrict__ accum,
                              const int* __restrict__ user,
                              const int* __restrict__ item,
                              const float* __restrict__ ubias,
                              const float* __restrict__ ibias,
                              const float* __restrict__ gb,
                              float* __restrict__ out) {
    const int b = blockIdx.x * blockDim.x + threadIdx.x;
    if (b < B_DIM) {
        float pred = accum[b] + ubias[user[b]] + ibias[item[b]] + gb[0];
        out[b] = 5.f / (1.f + expf(-pred));
    }
}

// ---------------------------------------------------------------------------
extern "C" void kernel_launch(void* const* d_in, const int* in_sizes, int n_in,
                              void* d_out, int out_size, void* d_ws, size_t ws_size,
                              hipStream_t stream) {
    const int*   user = (const int*)  d_in[0];
    const int*   item = (const int*)  d_in[1];
    const float* R    = (const float*)d_in[2];
    const float* S    = (const float*)d_in[3];
    const float* ubia = (const float*)d_in[4];
    const float* ibia = (const float*)d_in[5];
    const float* gb   = (const float*)d_in[6];
    float* out   = (float*)d_out;

    float*          accum = (float*)d_ws;                    // B_DIM f32
    unsigned short* Ag    = (unsigned short*)((char*)d_ws + (size_t)B_DIM * 4);

    size_t rg_bytes = (ws_size > (size_t)B_DIM * 4) ? ws_size - (size_t)B_DIM * 4 : 0;
    int max_rows = (int)(rg_bytes / ((size_t)B_DIM * 2));    // bf16 rows
    if (max_rows > U_DIM) max_rows = U_DIM;
    if (max_rows < 1)     max_rows = 1;

    hipMemsetAsync(accum, 0, B_DIM * sizeof(float), stream);

    for (int row0 = 0; row0 < U_DIM; row0 += max_rows) {
        const int nrows = min(max_rows, U_DIM - row0);
        gather_kernel<<<nrows, 1024, 0, stream>>>(R, item, Ag, row0);
        const int uchunk = 250;
        const int nuc = (nrows + uchunk - 1) / uchunk;
        dot2_kernel<<<dim3(B_DIM / 256, nuc), 256, 0, stream>>>(S, user, Ag, accum,
                                                                row0, nrows, uchunk);
    }

    finish_kernel<<<(B_DIM + 255) / 256, 256, 0, stream>>>(accum, user, item,
                                                           ubia, ibia, gb, out);
}